// Round 2
// baseline (363.680 us; speedup 1.0000x reference)
//
#include <hip/hip_runtime.h>
#include <hip/hip_bf16.h>
#include <cstdint>
#include <cstddef>

// YatDense: out[m,n] = (y^2 / (|x_m|^2 + |w_n|^2 - 2y + eps)) * scale + bias[n]
//   y = x[m,:] . w[n,:]   GEMM M=16384, N=2048, K=2048 (B^T layout input)
// R7: software-pipeline the 8-phase schedule. R6 serialized LDS-drain vs MFMA
// (reads issued and lgkm-drained in the SAME phase that consumes them ->
// MfmaUtil stuck at 41%). Now each phase pre-reads the NEXT phase's fragments
// into double-buffered regs (afA/afB, bfrA/bfrB) and MFMAs the current ones,
// so the LDS pipe drains p+1's reads while the matrix pipe runs p.
//  - One s_barrier per phase (was 2): stage-overwrite and seg-readiness each
//    still have >=1 barrier between producer and consumer (liveness re-derived).
//  - Stages: p1 A(b,both) | p2 B(a+2,0) | p3 B(a+2,1) | p5 A(a+2,both) |
//    p6 B(b+2,0) | p7 B(b+2,1).  bfr pre-reads split over two phases (p2/p3
//    read bfr(b), p6/p7 read bfr(a+2)) to even out LDS pressure (<=8 b128/ph).
//  - vmcnt(4) at end of p1/p3/p5/p7 leaves exactly the 4 youngest loads in
//    flight; drains precisely the segs whose first read is 1 phase later.
//    Tail iteration (skipped stages) falls back to vmcnt(0).
//  - sched_barrier(0) between read-issue and MFMA cluster pins the pipeline
//    (compiler would sink the loads to shrink register lifetime).
// prep: reworked to 1 wave/row (was 1 block/row): 2304 blocks, pure shuffle
// reduce, no LDS/syncthreads; prior version was the larger half of total time.

typedef __bf16 bf16_t;
typedef __bf16 bf16x8 __attribute__((ext_vector_type(8)));
typedef __bf16 bf16x4 __attribute__((ext_vector_type(4)));
typedef float f32x4 __attribute__((ext_vector_type(4)));

constexpr int M_DIM = 16384;  // B*S
constexpr int N_DIM = 2048;   // F
constexpr int K_DIM = 2048;   // D
constexpr int BM = 256, BN = 256, BK = 64;
constexpr int KT = K_DIM / BK;  // 32 K-tiles
constexpr int SEG = 128 * 64;   // seg elements (16 KB)

__device__ __forceinline__ void async16(const bf16_t* g, bf16_t* l) {
    __builtin_amdgcn_global_load_lds(
        (const __attribute__((address_space(1))) void*)g,
        (__attribute__((address_space(3))) void*)l,
        16, 0, 0);
}

// ---------------------------------------------------------------------------
// prep: one WAVE per row; 8 rows per 256-thread block; grid 2304.
// Per lane: 8x float4 (128 B) -> bf16x4 stores + fp32 sum of squares,
// wave shuffle-reduce, lane0 stores the norm. No LDS, no __syncthreads.
// ---------------------------------------------------------------------------
__global__ __launch_bounds__(256) void prep_convert(const float* __restrict__ x,
                                                    const float* __restrict__ w,
                                                    bf16_t* __restrict__ xb,
                                                    bf16_t* __restrict__ wb,
                                                    float* __restrict__ xsq,
                                                    float* __restrict__ wsq) {
    const int lane = threadIdx.x & 63;
    const int wv = threadIdx.x >> 6;
    const int base = blockIdx.x * 8 + wv * 2;
#pragma unroll
    for (int it = 0; it < 2; ++it) {
        const int row = base + it;
        const float* src;
        bf16_t* dstb;
        float* dsts;
        if (row < M_DIM) {
            src = x + (size_t)row * K_DIM;
            dstb = xb + (size_t)row * K_DIM;
            dsts = xsq + row;
        } else {
            const int r = row - M_DIM;
            src = w + (size_t)r * K_DIM;
            dstb = wb + (size_t)r * K_DIM;
            dsts = wsq + r;
        }
        const float4* s4 = (const float4*)src;
        bf16x4* d4 = (bf16x4*)dstb;
        float s = 0.0f;
#pragma unroll
        for (int j = 0; j < 8; ++j) {
            const float4 a = s4[lane + j * 64];
            s += a.x * a.x + a.y * a.y + a.z * a.z + a.w * a.w;
            bf16x4 v = { (bf16_t)a.x, (bf16_t)a.y, (bf16_t)a.z, (bf16_t)a.w };
            d4[lane + j * 64] = v;
        }
#pragma unroll
        for (int off = 32; off > 0; off >>= 1) s += __shfl_down(s, off, 64);
        if (lane == 0) *dsts = s;
    }
}

// ---------------------------------------------------------------------------
// 8-phase pipelined GEMM + Yat epilogue.
// ---------------------------------------------------------------------------
__global__ __launch_bounds__(512, 2) void yat_gemm(const bf16_t* __restrict__ A,   // [M,K] bf16 (ws)
                                                   const bf16_t* __restrict__ Bw,  // [N,K] bf16 (ws)
                                                   const float* __restrict__ xsq,  // [M]
                                                   const float* __restrict__ wsq,  // [N]
                                                   const float* __restrict__ bias,   // [N] fp32
                                                   const float* __restrict__ alpha,  // [1] fp32
                                                   float* __restrict__ out) {        // [M,N] fp32
    __shared__ bf16_t sA[4 * SEG];  // 64 KB, ring of 4 A row-half segs
    __shared__ bf16_t sB[4 * SEG];  // 64 KB, ring of 4 B row-half segs

    const int tid = (int)threadIdx.x;
    const int lane = tid & 63;
    const int wv = tid >> 6;   // 0..7
    const int wm = wv >> 2;    // 0..1 : wave row (128-row band)
    const int wn = wv & 3;     // 0..3 : wave col (64-col band)

    const int bm = (int)blockIdx.x >> 3;  // 0..63
    const int bn = (int)blockIdx.x & 7;   // 0..7

    // fragment addressing (mfma_f32_16x16x32_bf16):
    //  A: lane holds A[m=lane&15][k=(lane>>4)*8+j]; B mirrored ([n][k])
    //  C/D: col=lane&15, row=(lane>>4)*4+reg   [m89/m91-verified]
    const int frm = lane & 15;
    const int jch = lane >> 4;  // k-chunk 0..3 within a K=32 group
    const int sx = frm & 7;     // row-XOR for LDS swizzle

    // staging: thread t covers phys chunk (t&7) of seg row (t>>3) (+64 for
    // second load). LDS dest is LINEAR (t*16 B) as global_load_lds requires;
    // the global source chunk is inverse-permuted: g = (t&7) ^ (row&7).
    const int st_r = tid >> 3;  // 0..63
    const int st_g = (tid & 7) ^ (st_r & 7);
    const bf16_t* Ast = A + (size_t)(bm * BM + st_r) * K_DIM + st_g * 8;
    const bf16_t* Bst = Bw + (size_t)(bn * BN + st_r) * K_DIM + st_g * 8;

    auto stageA2 = [&](int kt) {  // both halves of A K-tile kt (4 loads)
        if (kt >= KT) return;
#pragma unroll
        for (int h = 0; h < 2; ++h) {
            bf16_t* d = sA + ((kt * 2 + h) & 3) * SEG + tid * 8;
            const bf16_t* s = Ast + (size_t)(h * 128) * K_DIM + kt * 64;
            async16(s, d);
            async16(s + (size_t)64 * K_DIM, d + 4096);
        }
    };
    auto stageB1 = [&](int kt, int h) {  // one half of B K-tile kt (2 loads)
        if (kt >= KT) return;
        bf16_t* d = sB + ((kt * 2 + h) & 3) * SEG + tid * 8;
        const bf16_t* s = Bst + (size_t)(h * 128) * K_DIM + kt * 64;
        async16(s, d);
        async16(s + (size_t)64 * K_DIM, d + 4096);
    };

    f32x4 acc[8][4] = {};
    bf16x8 afA[2][2], afB[2][2];    // [i2][kk] A frags, phase double-buffer
    bf16x8 bfrA[4][2], bfrB[4][2];  // [j][kk]  B frags, K-tile double-buffer

// af pre-read: frags for (tile KTN, quadrant QN) into DST
#define AF_READ(DST, KTN, QN)                                                  \
    {                                                                          \
        const int aslot_ = (((KTN) * 2 + wm) & 3) * SEG;                       \
        _Pragma("unroll") for (int i2 = 0; i2 < 2; ++i2)                       \
            _Pragma("unroll") for (int kk = 0; kk < 2; ++kk)                   \
                DST[i2][kk] = *(const bf16x8*)&sA[aslot_ +                     \
                    (((QN) * 2 + i2) * 16 + frm) * 64 + (((kk * 4 + jch) ^ sx) * 8)]; \
    }
// bfr pre-read: j = BJ0, BJ0+1 of tile KTB into DST
#define BF_READ(DST, BJ0, KTB)                                                 \
    {                                                                          \
        const int bslot_ = (((KTB) * 2 + (wn >> 1)) & 3) * SEG;                \
        _Pragma("unroll") for (int jj = 0; jj < 2; ++jj)                       \
            _Pragma("unroll") for (int kk = 0; kk < 2; ++kk)                   \
                DST[(BJ0) + jj][kk] = *(const bf16x8*)&sB[bslot_ +             \
                    ((wn & 1) * 64 + ((BJ0) + jj) * 16 + frm) * 64 +           \
                    (((kk * 4 + jch) ^ sx) * 8)];                              \
    }
#define MFMA16(QC, AFC, BFC)                                                   \
    __builtin_amdgcn_s_setprio(1);                                             \
    _Pragma("unroll") for (int kk = 0; kk < 2; ++kk)                           \
        _Pragma("unroll") for (int i2 = 0; i2 < 2; ++i2)                       \
            _Pragma("unroll") for (int j = 0; j < 4; ++j)                      \
                acc[(QC) * 2 + i2][j] = __builtin_amdgcn_mfma_f32_16x16x32_bf16( \
                    AFC[i2][kk], BFC[j][kk], acc[(QC) * 2 + i2][j], 0, 0, 0);  \
    __builtin_amdgcn_s_setprio(0);
#define SCHED0 __builtin_amdgcn_sched_barrier(0);
#define SBAR asm volatile("s_barrier" ::: "memory");
#define VMC4 asm volatile("s_waitcnt vmcnt(4)" ::: "memory");
#define VMC(SKT)                                                               \
    if ((SKT) < KT) { VMC4 } else { asm volatile("s_waitcnt vmcnt(0)" ::: "memory"); }

    // prologue: A(0), B(0), B(1) staged; drain A(0),B(0) (keep B(1) in
    // flight); read tile-0 frags (afA Q0 + bfrA).
    stageA2(0);
    stageB1(0, 0); stageB1(0, 1);
    stageB1(1, 0); stageB1(1, 1);
    VMC4
    SBAR
    AF_READ(afA, 0, 0)
    BF_READ(bfrA, 0, 0)
    BF_READ(bfrA, 2, 0)

#pragma unroll 1
    for (int u = 0; u < KT / 2; ++u) {
        const int a = 2 * u, b = a + 1;
        // p1: compute (a,Q0); pre-read (a,Q1); stage A(b)
        AF_READ(afB, a, 1)
        stageA2(b);
        SCHED0
        MFMA16(0, afA, bfrA)
        VMC4            // keep A(b); drains B(b) [staged prev p6/p7] for p2
        SBAR
        // p2: compute (a,Q1); pre-read (a,Q2) + bfr(b) lo; stage B(a+2,0)
        AF_READ(afA, a, 2)
        BF_READ(bfrB, 0, b)
        stageB1(a + 2, 0);
        SCHED0
        MFMA16(1, afB, bfrA)
        SBAR
        // p3: compute (a,Q2); pre-read (a,Q3) + bfr(b) hi; stage B(a+2,1)
        AF_READ(afB, a, 3)
        BF_READ(bfrB, 2, b)
        stageB1(a + 2, 1);
        SCHED0
        MFMA16(2, afA, bfrA)
        VMC(a + 2)      // keep B(a+2); drains A(b) for p4's pre-read
        SBAR
        // p4: compute (a,Q3); pre-read (b,Q0); no stage
        AF_READ(afA, b, 0)
        SCHED0
        MFMA16(3, afB, bfrA)
        SBAR
        // p5: compute (b,Q0); pre-read (b,Q1); stage A(a+2)
        AF_READ(afB, b, 1)
        stageA2(a + 2);
        SCHED0
        MFMA16(0, afA, bfrB)
        VMC(a + 2)      // keep A(a+2); drains B(a+2) for p6's bfr reads
        SBAR
        // p6: compute (b,Q1); pre-read (b,Q2) + bfr(a+2) lo; stage B(b+2,0)
        AF_READ(afA, b, 2)
        BF_READ(bfrA, 0, a + 2)
        stageB1(b + 2, 0);
        SCHED0
        MFMA16(1, afB, bfrB)
        SBAR
        // p7: compute (b,Q2); pre-read (b,Q3) + bfr(a+2) hi; stage B(b+2,1)
        AF_READ(afB, b, 3)
        BF_READ(bfrA, 2, a + 2)
        stageB1(b + 2, 1);
        SCHED0
        MFMA16(2, afA, bfrB)
        VMC(b + 2)      // keep B(b+2); drains A(a+2) for p8's pre-read
        SBAR
        // p8: compute (b,Q3); pre-read (a+2,Q0); no stage
        AF_READ(afA, a + 2, 0)
        SCHED0
        MFMA16(3, afB, bfrB)
        SBAR
    }
#undef AF_READ
#undef BF_READ
#undef MFMA16
#undef SCHED0
#undef SBAR
#undef VMC4
#undef VMC

    // epilogue (fp32 stores)
    const float sc = powf(sqrtf((float)N_DIM) / logf(1.0f + (float)N_DIM), alpha[0]);
    float wsq_c[4], bias_c[4];
#pragma unroll
    for (int j = 0; j < 4; ++j) {
        const int col = bn * BN + wn * 64 + j * 16 + frm;
        wsq_c[j] = wsq[col];
        bias_c[j] = bias[col];
    }
#pragma unroll
    for (int i = 0; i < 8; ++i) {
#pragma unroll
        for (int r = 0; r < 4; ++r) {
            const int row = bm * BM + wm * 128 + i * 16 + jch * 4 + r;
            const float xs = xsq[row];
            float* orow = out + (size_t)row * N_DIM + bn * BN + wn * 64 + frm;
#pragma unroll
            for (int j = 0; j < 4; ++j) {
                const float y = acc[i][j][r];
                const float d = xs + wsq_c[j] - 2.0f * y + 1e-6f;
                orow[j * 16] = (y * y) / d * sc + bias_c[j];
            }
        }
    }
}

extern "C" void kernel_launch(void* const* d_in, const int* in_sizes, int n_in,
                              void* d_out, int out_size, void* d_ws, size_t ws_size,
                              hipStream_t stream) {
    (void)in_sizes; (void)n_in; (void)out_size; (void)ws_size;
    const float* x = (const float*)d_in[0];      // [16384, 2048] fp32
    const float* w = (const float*)d_in[1];      // [2048, 2048] fp32
    const float* alpha = (const float*)d_in[2];  // [1] fp32
    const float* bias = (const float*)d_in[3];   // [2048] fp32
    float* out = (float*)d_out;                  // [16384, 2048] fp32

    // ws layout: xb (33.5M bf16), wb (4.2M bf16), xsq (16384 f32), wsq (2048 f32)
    bf16_t* xb = (bf16_t*)d_ws;
    bf16_t* wb = xb + (size_t)M_DIM * K_DIM;
    float* xsq = (float*)(wb + (size_t)N_DIM * K_DIM);
    float* wsq = xsq + M_DIM;

    prep_convert<<<(M_DIM + N_DIM) / 8, 256, 0, stream>>>(x, w, xb, wb, xsq, wsq);
    yat_gemm<<<(M_DIM / BM) * (N_DIM / BN), 512, 0, stream>>>(xb, wb, xsq, wsq, bias, alpha, out);
}